// Round 13
// baseline (495.795 us; speedup 1.0000x reference)
//
#include <hip/hip_runtime.h>
#include <hip/hip_bf16.h>
#include <stdint.h>

#define NN 100000
#define NE 1000000
#define DIM 128
#define NLAB 2048

typedef __attribute__((ext_vector_type(8))) short bf16x8;
typedef __attribute__((ext_vector_type(4))) float f32x4;
typedef __attribute__((ext_vector_type(2))) unsigned short us2;
typedef __attribute__((ext_vector_type(4))) unsigned short us4;
typedef __attribute__((ext_vector_type(8))) unsigned short us8;

__device__ __forceinline__ unsigned short f2bf(float f){
    union { float f; unsigned int u; } v; v.f = f;
    unsigned int r = v.u + 0x7FFFu + ((v.u >> 16) & 1u);   // round-to-nearest-even
    return (unsigned short)(r >> 16);
}
__device__ __forceinline__ float bf2f(unsigned short b){
    union { unsigned int u; float f; } v; v.u = ((unsigned int)b) << 16;
    return v.f;
}

// ---------- fused setup: gather+convert | Wout transpose | edge count/deg ----------
#define NB_GATHER 12500   // NN*32/256
#define NB_WT 256
#define NB_COUNT 3907     // ceil(NE/256)
__global__ __launch_bounds__(256) void k_setup(const int* __restrict__ ni,
                                               const float* __restrict__ emb,
                                               unsigned short* __restrict__ xbf,
                                               const float* __restrict__ W,
                                               unsigned short* __restrict__ Wt,
                                               const int* __restrict__ col,
                                               const float* __restrict__ ew,
                                               int* __restrict__ cnt,
                                               float* __restrict__ deg){
    __shared__ float t[32][33];
    int b = blockIdx.x;
    if(b < NB_GATHER){
        int id = b*256 + threadIdx.x;           // NN*32 threads, 4 elems each
        int i = id >> 5, q = (id & 31) << 2;
        float4 v = *reinterpret_cast<const float4*>(&emb[(long)ni[i]*DIM + q]);
        us4 o; o.x = f2bf(v.x); o.y = f2bf(v.y); o.z = f2bf(v.z); o.w = f2bf(v.w);
        *reinterpret_cast<us4*>(&xbf[(long)i*DIM + q]) = o;
    } else if(b < NB_GATHER + NB_WT){
        int bb = b - NB_GATHER;
        int kb = bb & 3;      // 128/32
        int cb = bb >> 2;     // 2048/32
        int ci = threadIdx.x & 31;
        int k0 = threadIdx.x >> 5;
        #pragma unroll
        for(int p=0; p<4; ++p){
            int ki = k0 + p*8;
            t[ki][ci] = W[(long)(kb*32+ki)*NLAB + cb*32 + ci];
        }
        __syncthreads();
        int kk = threadIdx.x & 31;
        int c0 = threadIdx.x >> 5;
        #pragma unroll
        for(int p=0; p<4; ++p){
            int cc = c0 + p*8;
            Wt[(long)(cb*32+cc)*DIM + kb*32 + kk] = f2bf(t[kk][cc]);
        }
    } else {
        int e = (b - NB_GATHER - NB_WT)*256 + threadIdx.x;
        if(e < NE){
            int c = col[e];
            atomicAdd(&cnt[c], 1);
            atomicAdd(&deg[c], ew[e]);
        }
    }
}

// ---------- CSR scans ----------
__global__ void k_scan1(const int* __restrict__ cnt, int* __restrict__ excl,
                        int* __restrict__ bsum){
    __shared__ int s[256];
    int tid = threadIdx.x;
    int i = blockIdx.x*256 + tid;
    int v = (i < NN) ? cnt[i] : 0;
    int x = v;
    s[tid] = x; __syncthreads();
    for(int off=1; off<256; off<<=1){
        int t = (tid >= off) ? s[tid-off] : 0;
        __syncthreads();
        x += t; s[tid] = x;
        __syncthreads();
    }
    if(i < NN) excl[i] = x - v;
    if(tid == 255) bsum[blockIdx.x] = x;
}

#define NB_SCAN1 391
__global__ __launch_bounds__(512) void k_scan23(const int* __restrict__ excl,
                                                const int* __restrict__ bsum,
                                                int* __restrict__ start,
                                                int* __restrict__ cursor,
                                                const float* __restrict__ deg,
                                                float* __restrict__ dinv){
    __shared__ int s[512];
    int tid = threadIdx.x;
    int v = (tid < NB_SCAN1) ? bsum[tid] : 0;
    int x = v;
    s[tid] = x; __syncthreads();
    for(int off=1; off<512; off<<=1){
        int t = (tid >= off) ? s[tid-off] : 0;
        __syncthreads();
        x += t; s[tid] = x;
        __syncthreads();
    }
    int i = blockIdx.x*512 + tid;
    if(i < NN){
        int pb = i >> 8;
        int bpre = pb ? s[pb-1] : 0;
        int st = excl[i] + bpre;
        start[i] = st; cursor[i] = st;
        float d = deg[i] + 1.0f;                // self-loop weight 1
        dinv[i] = rsqrtf(d);
    }
    if(i == 0) start[NN] = NE;
}

// ---------- fused layer-1 GEMM + CSR fill ----------
#define NB_G128 1563      // ceil(NN/64)
__global__ __launch_bounds__(256) void k_l1(const unsigned short* __restrict__ X,
                                            const float* __restrict__ W,
                                            unsigned short* __restrict__ H,
                                            const int* __restrict__ row,
                                            const int* __restrict__ col,
                                            const float* __restrict__ ew,
                                            const float* __restrict__ dinv,
                                            int* __restrict__ cursor,
                                            int2* __restrict__ epack){
    __shared__ unsigned short Wt[DIM][DIM+8];   // [col][k], padded
    int tid = threadIdx.x;
    if(blockIdx.x >= NB_G128){
        int e = (blockIdx.x - NB_G128)*256 + tid;
        if(e < NE){
            int c = col[e];
            int r = row[e];
            float wn = ew[e] * dinv[r];
            int p = atomicAdd(&cursor[c], 1);
            epack[p] = make_int2(r, __float_as_int(wn));
        }
        return;
    }
    #pragma unroll
    for(int t=0; t<64; ++t){
        int idx = tid + t*256;                  // 16384 elems
        int k = idx >> 7, j = idx & 127;
        Wt[j][k] = f2bf(W[k*DIM + j]);
    }
    __syncthreads();

    int lane = tid & 63, w = tid >> 6;
    int rowbase = blockIdx.x*64 + w*16;
    int r16 = lane & 15, ksel = lane >> 4;
    int arow = rowbase + r16; if(arow > NN-1) arow = NN-1;
    const unsigned short* xr = X + (long)arow*DIM;
    bf16x8 a[4];
    #pragma unroll
    for(int ks=0; ks<4; ++ks)
        a[ks] = *reinterpret_cast<const bf16x8*>(&xr[ks*32 + ksel*8]);

    f32x4 acc[8] = {};
    #pragma unroll
    for(int ks=0; ks<4; ++ks){
        #pragma unroll
        for(int nt=0; nt<8; ++nt){
            bf16x8 b = *reinterpret_cast<const bf16x8*>(&Wt[nt*16 + r16][ks*32 + ksel*8]);
            acc[nt] = __builtin_amdgcn_mfma_f32_16x16x32_bf16(a[ks], b, acc[nt], 0, 0, 0);
        }
    }

    int orow0 = rowbase + ksel*4;
    #pragma unroll
    for(int nt=0; nt<8; ++nt){
        int oc = nt*16 + r16;
        #pragma unroll
        for(int r=0; r<4; ++r){
            int orow = orow0 + r;
            if(orow < NN) H[(long)orow*DIM + oc] = f2bf(acc[nt][r]);
        }
    }
}

// ---------- H = X @ W  (NNx128 @ 128x128, bf16 in, bf16 out) ----------
__global__ __launch_bounds__(256) void k_gemm128(const unsigned short* __restrict__ X,
                                                 const float* __restrict__ W,
                                                 unsigned short* __restrict__ H){
    __shared__ unsigned short Wt[DIM][DIM+8];   // [col][k], padded
    int tid = threadIdx.x;
    #pragma unroll
    for(int t=0; t<64; ++t){
        int idx = tid + t*256;                  // 16384 elems
        int k = idx >> 7, j = idx & 127;
        Wt[j][k] = f2bf(W[k*DIM + j]);
    }
    __syncthreads();

    int lane = tid & 63, w = tid >> 6;
    int rowbase = blockIdx.x*64 + w*16;
    int r16 = lane & 15, ksel = lane >> 4;
    int arow = rowbase + r16; if(arow > NN-1) arow = NN-1;
    const unsigned short* xr = X + (long)arow*DIM;
    bf16x8 a[4];
    #pragma unroll
    for(int ks=0; ks<4; ++ks)
        a[ks] = *reinterpret_cast<const bf16x8*>(&xr[ks*32 + ksel*8]);

    f32x4 acc[8] = {};
    #pragma unroll
    for(int ks=0; ks<4; ++ks){
        #pragma unroll
        for(int nt=0; nt<8; ++nt){
            bf16x8 b = *reinterpret_cast<const bf16x8*>(&Wt[nt*16 + r16][ks*32 + ksel*8]);
            acc[nt] = __builtin_amdgcn_mfma_f32_16x16x32_bf16(a[ks], b, acc[nt], 0, 0, 0);
        }
    }

    int orow0 = rowbase + ksel*4;
    #pragma unroll
    for(int nt=0; nt<8; ++nt){
        int oc = nt*16 + r16;
        #pragma unroll
        for(int r=0; r<4; ++r){
            int orow = orow0 + r;
            if(orow < NN) H[(long)orow*DIM + oc] = f2bf(acc[nt][r]);
        }
    }
}

// ---------- fused aggregation: 16 edges in flight per wave ----------
__global__ void k_agg(const unsigned short* __restrict__ H, const int* __restrict__ start,
                      const int2* __restrict__ epack,
                      const float* __restrict__ dinv, const float* __restrict__ bias,
                      unsigned short* __restrict__ Xo){
    int wid  = (blockIdx.x*256 + threadIdx.x) >> 6;   // one wave per node
    int lane = threadIdx.x & 63;
    if(wid >= NN) return;
    int c = wid;
    int q = lane >> 4;
    int f = lane & 15;
    int s = start[c], e = start[c+1];
    float acc[8] = {0.f,0.f,0.f,0.f,0.f,0.f,0.f,0.f};
    for(int p=s; p<e; p+=16){
        int pe0 = p + q, pe1 = p + q + 4, pe2 = p + q + 8, pe3 = p + q + 12;
        int pc0 = pe0 < e ? pe0 : e-1;
        int pc1 = pe1 < e ? pe1 : e-1;
        int pc2 = pe2 < e ? pe2 : e-1;
        int pc3 = pe3 < e ? pe3 : e-1;
        int2 k0 = epack[pc0];
        int2 k1 = epack[pc1];
        int2 k2 = epack[pc2];
        int2 k3 = epack[pc3];
        float sc0 = pe0 < e ? __int_as_float(k0.y) : 0.f;
        float sc1 = pe1 < e ? __int_as_float(k1.y) : 0.f;
        float sc2 = pe2 < e ? __int_as_float(k2.y) : 0.f;
        float sc3 = pe3 < e ? __int_as_float(k3.y) : 0.f;
        us8 h0 = *reinterpret_cast<const us8*>(&H[(long)k0.x*DIM + f*8]);
        us8 h1 = *reinterpret_cast<const us8*>(&H[(long)k1.x*DIM + f*8]);
        us8 h2 = *reinterpret_cast<const us8*>(&H[(long)k2.x*DIM + f*8]);
        us8 h3 = *reinterpret_cast<const us8*>(&H[(long)k3.x*DIM + f*8]);
        #pragma unroll
        for(int j=0;j<8;++j)
            acc[j] += (sc0 * bf2f(h0[j]) + sc1 * bf2f(h1[j]))
                    + (sc2 * bf2f(h2[j]) + sc3 * bf2f(h3[j]));
    }
    #pragma unroll
    for(int j=0;j<8;++j){
        acc[j] += __shfl_xor(acc[j], 16);
        acc[j] += __shfl_xor(acc[j], 32);
    }
    if(q == 0){
        float dc = dinv[c];
        us8 hc = *reinterpret_cast<const us8*>(&H[(long)c*DIM + f*8]);
        us8 o;
        #pragma unroll
        for(int j=0;j<8;++j){
            float v = dc*(acc[j] + dc*bf2f(hc[j])) + bias[f*8+j];
            v = v > 0.f ? v : 0.f;
            o[j] = f2bf(v);
        }
        *reinterpret_cast<us8*>(&Xo[(long)c*DIM + f*8]) = o;
    }
}

// ---------- out = X @ Wout + bout ----------
// Contiguous-store epilogue (wave-private LDS transpose, no barrier).
// A/B this round: PLAIN stores (through L2, full-line coverage) vs NT.
#define RT_PER_BLK 4
#define GRID_OUT 6256          // 391 rtg * 16 colg, divisible by 8
#define OBS 132                // f32 stride of Ob row (16B-aligned, bank-uniform)
__global__ __launch_bounds__(256) void k_gemm_out(const unsigned short* __restrict__ X,
                                                  const unsigned short* __restrict__ Wt,
                                                  const float* __restrict__ bout,
                                                  float* __restrict__ out){
    __shared__ unsigned short Wl[128*136];      // [col][k], 34816 B
    __shared__ float Ob[4*16*OBS];              // 4 wave-private 16x132 slices, 33792 B
    int obid = (blockIdx.x & 7)*(GRID_OUT/8) + (blockIdx.x >> 3);
    int colg = obid & 15;                       // 16 col groups of 128
    int rtg  = obid >> 4;                       // row-tile group
    int colbase = colg * 128;
    int tid = threadIdx.x;

    #pragma unroll
    for(int i=0; i<8; ++i){
        int chunk = i*256 + tid;                // 0..2047, 8 us each
        int r = chunk >> 4, seg = chunk & 15;
        bf16x8 v = *reinterpret_cast<const bf16x8*>(Wt + (long)(colbase + r)*DIM + seg*8);
        *reinterpret_cast<bf16x8*>(&Wl[r*136 + seg*8]) = v;
    }
    __syncthreads();

    int lane = tid & 63, w = tid >> 6;
    int r16 = lane & 15, ksel = lane >> 4;
    float* ob = Ob + w*16*OBS;
    int l32 = lane & 31, lh = lane >> 5;

    bf16x8 bcur[4], bnext[4];
    {
        int row0 = (rtg*RT_PER_BLK + 0)*64 + w*16 + r16;
        int arow = row0 < NN ? row0 : NN-1;
        const unsigned short* xr = X + (long)arow*DIM + ksel*8;
        #pragma unroll
        for(int ks=0; ks<4; ++ks) bcur[ks] = *reinterpret_cast<const bf16x8*>(xr + ks*32);
    }

    #pragma unroll 1
    for(int it=0; it<RT_PER_BLK; ++it){
        int tilebase = (rtg*RT_PER_BLK + it)*64;
        int row = tilebase + w*16 + r16;
        // prefetch next row-tile's X fragments
        if(it+1 < RT_PER_BLK){
            int rown = row + 64;
            int arow = rown < NN ? rown : NN-1;
            const unsigned short* xr = X + (long)arow*DIM + ksel*8;
            #pragma unroll
            for(int ks=0; ks<4; ++ks) bnext[ks] = *reinterpret_cast<const bf16x8*>(xr + ks*32);
        }

        f32x4 acc[8] = {};
        #pragma unroll
        for(int nt=0; nt<8; ++nt){
            const unsigned short* wl = &Wl[(nt*16 + r16)*136 + ksel*8];
            #pragma unroll
            for(int ks=0; ks<4; ++ks){
                bf16x8 a = *reinterpret_cast<const bf16x8*>(wl + ks*32);
                acc[nt] = __builtin_amdgcn_mfma_f32_16x16x32_bf16(a, bcur[ks], acc[nt], 0, 0, 0);
            }
        }

        // epilogue: bias -> wave-private LDS (row r16) -> contiguous PLAIN stores
        {
            const float* br = bout + colbase + ksel*4;
            #pragma unroll
            for(int nt=0; nt<8; ++nt){
                f32x4 bv = *reinterpret_cast<const f32x4*>(br + nt*16);
                f32x4 v = acc[nt] + bv;
                *reinterpret_cast<f32x4*>(&ob[r16*OBS + nt*16 + ksel*4]) = v;
            }
            // same wave reads its own slice: in-order LDS per wave, no barrier
            #pragma unroll
            for(int i=0; i<8; ++i){
                int lr = i*2 + lh;
                int grow = tilebase + w*16 + lr;
                f32x4 v = *reinterpret_cast<const f32x4*>(&ob[lr*OBS + l32*4]);
                if(grow < NN)
                    *reinterpret_cast<f32x4*>(out + (long)grow*NLAB + colbase + l32*4) = v;
            }
        }
        #pragma unroll
        for(int ks=0; ks<4; ++ks) bcur[ks] = bnext[ks];
    }
}

extern "C" void kernel_launch(void* const* d_in, const int* in_sizes, int n_in,
                              void* d_out, int out_size, void* d_ws, size_t ws_size,
                              hipStream_t stream){
    const int*   ni  = (const int*)  d_in[0];
    const int*   ei  = (const int*)  d_in[1];
    const float* ew  = (const float*)d_in[2];
    const float* emb = (const float*)d_in[3];
    const float* W1  = (const float*)d_in[4];
    const float* b1  = (const float*)d_in[5];
    const float* W2  = (const float*)d_in[6];
    const float* b2  = (const float*)d_in[7];
    const float* Wo  = (const float*)d_in[8];
    const float* bo  = (const float*)d_in[9];
    float* out = (float*)d_out;
    const int* row = ei;
    const int* col = ei + NE;

    char* ws = (char*)d_ws;
    size_t off = 0;
    auto alloc = [&](size_t bytes){ void* p = ws + off; off += (bytes + 255) & ~size_t(255); return p; };
    int*   cnt    = (int*)  alloc((size_t)NN*8);     // cnt[NN] + deg[NN] contiguous (one memset)
    float* deg    = (float*)(cnt + NN);
    int*   excl   = (int*)  alloc((size_t)NN*4);
    int*   bsum   = (int*)  alloc(512*4);
    int*   start  = (int*)  alloc((size_t)(NN+1)*4);
    int*   cursor = (int*)  alloc((size_t)NN*4);
    float* dinv   = (float*)alloc((size_t)NN*4);
    int2*  epack  = (int2*) alloc((size_t)NE*8);
    unsigned short* Xbf = (unsigned short*)alloc((size_t)NN*DIM*2);
    unsigned short* Hbf = (unsigned short*)alloc((size_t)NN*DIM*2);
    unsigned short* Wot = (unsigned short*)alloc((size_t)NLAB*DIM*2);

    const int nbN = (NN + 255)/256;             // 391

    hipMemsetAsync(cnt, 0, (size_t)NN*8, stream);
    k_setup <<<NB_GATHER + NB_WT + NB_COUNT, 256, 0, stream>>>(ni, emb, Xbf, Wo, Wot, col, ew, cnt, deg);
    k_scan1 <<<nbN, 256, 0, stream>>>(cnt, excl, bsum);
    k_scan23<<<(NN + 511)/512, 512, 0, stream>>>(excl, bsum, start, cursor, deg, dinv);

    // layer 1 GEMM fused with CSR fill (independent after scan23)
    k_l1    <<<NB_G128 + NB_COUNT, 256, 0, stream>>>(Xbf, W1, Hbf, row, col, ew, dinv, cursor, epack);
    k_agg   <<<(NN*64+255)/256, 256, 0, stream>>>(Hbf, start, epack, dinv, b1, Xbf);
    // layer 2
    k_gemm128<<<NB_G128, 256, 0, stream>>>(Xbf, W2, Hbf);
    k_agg    <<<(NN*64+255)/256, 256, 0, stream>>>(Hbf, start, epack, dinv, b2, Xbf);
    // output projection
    k_gemm_out<<<GRID_OUT, 256, 0, stream>>>(Xbf, Wot, bo, out);
}

// Round 14
// 450.443 us; speedup vs baseline: 1.1007x; 1.1007x over previous
//
#include <hip/hip_runtime.h>
#include <hip/hip_bf16.h>
#include <stdint.h>

#define NN 100000
#define NE 1000000
#define DIM 128
#define NLAB 2048

typedef __attribute__((ext_vector_type(8))) short bf16x8;
typedef __attribute__((ext_vector_type(4))) float f32x4;
typedef __attribute__((ext_vector_type(2))) unsigned short us2;
typedef __attribute__((ext_vector_type(4))) unsigned short us4;
typedef __attribute__((ext_vector_type(8))) unsigned short us8;

__device__ __forceinline__ unsigned short f2bf(float f){
    union { float f; unsigned int u; } v; v.f = f;
    unsigned int r = v.u + 0x7FFFu + ((v.u >> 16) & 1u);   // round-to-nearest-even
    return (unsigned short)(r >> 16);
}
__device__ __forceinline__ float bf2f(unsigned short b){
    union { unsigned int u; float f; } v; v.u = ((unsigned int)b) << 16;
    return v.f;
}

// ---------- fused setup: gather+convert | Wout transpose | edge count/deg ----------
#define NB_GATHER 12500   // NN*32/256
#define NB_WT 256
#define NB_COUNT 3907     // ceil(NE/256)
__global__ __launch_bounds__(256) void k_setup(const int* __restrict__ ni,
                                               const float* __restrict__ emb,
                                               unsigned short* __restrict__ xbf,
                                               const float* __restrict__ W,
                                               unsigned short* __restrict__ Wt,
                                               const int* __restrict__ col,
                                               const float* __restrict__ ew,
                                               int* __restrict__ cnt,
                                               float* __restrict__ deg){
    __shared__ float t[32][33];
    int b = blockIdx.x;
    if(b < NB_GATHER){
        int id = b*256 + threadIdx.x;           // NN*32 threads, 4 elems each
        int i = id >> 5, q = (id & 31) << 2;
        float4 v = *reinterpret_cast<const float4*>(&emb[(long)ni[i]*DIM + q]);
        us4 o; o.x = f2bf(v.x); o.y = f2bf(v.y); o.z = f2bf(v.z); o.w = f2bf(v.w);
        *reinterpret_cast<us4*>(&xbf[(long)i*DIM + q]) = o;
    } else if(b < NB_GATHER + NB_WT){
        int bb = b - NB_GATHER;
        int kb = bb & 3;      // 128/32
        int cb = bb >> 2;     // 2048/32
        int ci = threadIdx.x & 31;
        int k0 = threadIdx.x >> 5;
        #pragma unroll
        for(int p=0; p<4; ++p){
            int ki = k0 + p*8;
            t[ki][ci] = W[(long)(kb*32+ki)*NLAB + cb*32 + ci];
        }
        __syncthreads();
        int kk = threadIdx.x & 31;
        int c0 = threadIdx.x >> 5;
        #pragma unroll
        for(int p=0; p<4; ++p){
            int cc = c0 + p*8;
            Wt[(long)(cb*32+cc)*DIM + kb*32 + kk] = f2bf(t[kk][cc]);
        }
    } else {
        int e = (b - NB_GATHER - NB_WT)*256 + threadIdx.x;
        if(e < NE){
            int c = col[e];
            atomicAdd(&cnt[c], 1);
            atomicAdd(&deg[c], ew[e]);
        }
    }
}

// ---------- CSR scans ----------
__global__ void k_scan1(const int* __restrict__ cnt, int* __restrict__ excl,
                        int* __restrict__ bsum){
    __shared__ int s[256];
    int tid = threadIdx.x;
    int i = blockIdx.x*256 + tid;
    int v = (i < NN) ? cnt[i] : 0;
    int x = v;
    s[tid] = x; __syncthreads();
    for(int off=1; off<256; off<<=1){
        int t = (tid >= off) ? s[tid-off] : 0;
        __syncthreads();
        x += t; s[tid] = x;
        __syncthreads();
    }
    if(i < NN) excl[i] = x - v;
    if(tid == 255) bsum[blockIdx.x] = x;
}

#define NB_SCAN1 391
__global__ __launch_bounds__(512) void k_scan23(const int* __restrict__ excl,
                                                const int* __restrict__ bsum,
                                                int* __restrict__ start,
                                                int* __restrict__ cursor,
                                                const float* __restrict__ deg,
                                                float* __restrict__ dinv){
    __shared__ int s[512];
    int tid = threadIdx.x;
    int v = (tid < NB_SCAN1) ? bsum[tid] : 0;
    int x = v;
    s[tid] = x; __syncthreads();
    for(int off=1; off<512; off<<=1){
        int t = (tid >= off) ? s[tid-off] : 0;
        __syncthreads();
        x += t; s[tid] = x;
        __syncthreads();
    }
    int i = blockIdx.x*512 + tid;
    if(i < NN){
        int pb = i >> 8;
        int bpre = pb ? s[pb-1] : 0;
        int st = excl[i] + bpre;
        start[i] = st; cursor[i] = st;
        float d = deg[i] + 1.0f;                // self-loop weight 1
        dinv[i] = rsqrtf(d);
    }
    if(i == 0) start[NN] = NE;
}

// ---------- fused layer-1 GEMM + CSR fill ----------
#define NB_G128 1563      // ceil(NN/64)
__global__ __launch_bounds__(256) void k_l1(const unsigned short* __restrict__ X,
                                            const float* __restrict__ W,
                                            unsigned short* __restrict__ H,
                                            const int* __restrict__ row,
                                            const int* __restrict__ col,
                                            const float* __restrict__ ew,
                                            const float* __restrict__ dinv,
                                            int* __restrict__ cursor,
                                            int2* __restrict__ epack){
    __shared__ unsigned short Wt[DIM][DIM+8];   // [col][k], padded
    int tid = threadIdx.x;
    if(blockIdx.x >= NB_G128){
        int e = (blockIdx.x - NB_G128)*256 + tid;
        if(e < NE){
            int c = col[e];
            int r = row[e];
            float wn = ew[e] * dinv[r];
            int p = atomicAdd(&cursor[c], 1);
            epack[p] = make_int2(r, __float_as_int(wn));
        }
        return;
    }
    #pragma unroll
    for(int t=0; t<64; ++t){
        int idx = tid + t*256;                  // 16384 elems
        int k = idx >> 7, j = idx & 127;
        Wt[j][k] = f2bf(W[k*DIM + j]);
    }
    __syncthreads();

    int lane = tid & 63, w = tid >> 6;
    int rowbase = blockIdx.x*64 + w*16;
    int r16 = lane & 15, ksel = lane >> 4;
    int arow = rowbase + r16; if(arow > NN-1) arow = NN-1;
    const unsigned short* xr = X + (long)arow*DIM;
    bf16x8 a[4];
    #pragma unroll
    for(int ks=0; ks<4; ++ks)
        a[ks] = *reinterpret_cast<const bf16x8*>(&xr[ks*32 + ksel*8]);

    f32x4 acc[8] = {};
    #pragma unroll
    for(int ks=0; ks<4; ++ks){
        #pragma unroll
        for(int nt=0; nt<8; ++nt){
            bf16x8 b = *reinterpret_cast<const bf16x8*>(&Wt[nt*16 + r16][ks*32 + ksel*8]);
            acc[nt] = __builtin_amdgcn_mfma_f32_16x16x32_bf16(a[ks], b, acc[nt], 0, 0, 0);
        }
    }

    int orow0 = rowbase + ksel*4;
    #pragma unroll
    for(int nt=0; nt<8; ++nt){
        int oc = nt*16 + r16;
        #pragma unroll
        for(int r=0; r<4; ++r){
            int orow = orow0 + r;
            if(orow < NN) H[(long)orow*DIM + oc] = f2bf(acc[nt][r]);
        }
    }
}

// ---------- H = X @ W  (NNx128 @ 128x128, bf16 in, bf16 out) ----------
__global__ __launch_bounds__(256) void k_gemm128(const unsigned short* __restrict__ X,
                                                 const float* __restrict__ W,
                                                 unsigned short* __restrict__ H){
    __shared__ unsigned short Wt[DIM][DIM+8];   // [col][k], padded
    int tid = threadIdx.x;
    #pragma unroll
    for(int t=0; t<64; ++t){
        int idx = tid + t*256;                  // 16384 elems
        int k = idx >> 7, j = idx & 127;
        Wt[j][k] = f2bf(W[k*DIM + j]);
    }
    __syncthreads();

    int lane = tid & 63, w = tid >> 6;
    int rowbase = blockIdx.x*64 + w*16;
    int r16 = lane & 15, ksel = lane >> 4;
    int arow = rowbase + r16; if(arow > NN-1) arow = NN-1;
    const unsigned short* xr = X + (long)arow*DIM;
    bf16x8 a[4];
    #pragma unroll
    for(int ks=0; ks<4; ++ks)
        a[ks] = *reinterpret_cast<const bf16x8*>(&xr[ks*32 + ksel*8]);

    f32x4 acc[8] = {};
    #pragma unroll
    for(int ks=0; ks<4; ++ks){
        #pragma unroll
        for(int nt=0; nt<8; ++nt){
            bf16x8 b = *reinterpret_cast<const bf16x8*>(&Wt[nt*16 + r16][ks*32 + ksel*8]);
            acc[nt] = __builtin_amdgcn_mfma_f32_16x16x32_bf16(a[ks], b, acc[nt], 0, 0, 0);
        }
    }

    int orow0 = rowbase + ksel*4;
    #pragma unroll
    for(int nt=0; nt<8; ++nt){
        int oc = nt*16 + r16;
        #pragma unroll
        for(int r=0; r<4; ++r){
            int orow = orow0 + r;
            if(orow < NN) H[(long)orow*DIM + oc] = f2bf(acc[nt][r]);
        }
    }
}

// ---------- fused aggregation: 16 edges in flight per wave ----------
__global__ void k_agg(const unsigned short* __restrict__ H, const int* __restrict__ start,
                      const int2* __restrict__ epack,
                      const float* __restrict__ dinv, const float* __restrict__ bias,
                      unsigned short* __restrict__ Xo){
    int wid  = (blockIdx.x*256 + threadIdx.x) >> 6;   // one wave per node
    int lane = threadIdx.x & 63;
    if(wid >= NN) return;
    int c = wid;
    int q = lane >> 4;
    int f = lane & 15;
    int s = start[c], e = start[c+1];
    float acc[8] = {0.f,0.f,0.f,0.f,0.f,0.f,0.f,0.f};
    for(int p=s; p<e; p+=16){
        int pe0 = p + q, pe1 = p + q + 4, pe2 = p + q + 8, pe3 = p + q + 12;
        int pc0 = pe0 < e ? pe0 : e-1;
        int pc1 = pe1 < e ? pe1 : e-1;
        int pc2 = pe2 < e ? pe2 : e-1;
        int pc3 = pe3 < e ? pe3 : e-1;
        int2 k0 = epack[pc0];
        int2 k1 = epack[pc1];
        int2 k2 = epack[pc2];
        int2 k3 = epack[pc3];
        float sc0 = pe0 < e ? __int_as_float(k0.y) : 0.f;
        float sc1 = pe1 < e ? __int_as_float(k1.y) : 0.f;
        float sc2 = pe2 < e ? __int_as_float(k2.y) : 0.f;
        float sc3 = pe3 < e ? __int_as_float(k3.y) : 0.f;
        us8 h0 = *reinterpret_cast<const us8*>(&H[(long)k0.x*DIM + f*8]);
        us8 h1 = *reinterpret_cast<const us8*>(&H[(long)k1.x*DIM + f*8]);
        us8 h2 = *reinterpret_cast<const us8*>(&H[(long)k2.x*DIM + f*8]);
        us8 h3 = *reinterpret_cast<const us8*>(&H[(long)k3.x*DIM + f*8]);
        #pragma unroll
        for(int j=0;j<8;++j)
            acc[j] += (sc0 * bf2f(h0[j]) + sc1 * bf2f(h1[j]))
                    + (sc2 * bf2f(h2[j]) + sc3 * bf2f(h3[j]));
    }
    #pragma unroll
    for(int j=0;j<8;++j){
        acc[j] += __shfl_xor(acc[j], 16);
        acc[j] += __shfl_xor(acc[j], 32);
    }
    if(q == 0){
        float dc = dinv[c];
        us8 hc = *reinterpret_cast<const us8*>(&H[(long)c*DIM + f*8]);
        us8 o;
        #pragma unroll
        for(int j=0;j<8;++j){
            float v = dc*(acc[j] + dc*bf2f(hc[j])) + bias[f*8+j];
            v = v > 0.f ? v : 0.f;
            o[j] = f2bf(v);
        }
        *reinterpret_cast<us8*>(&Xo[(long)c*DIM + f*8]) = o;
    }
}

// ---------- out = X @ Wout + bout ----------
// NT + contiguous epilogue (validated best, R12). Ob halved: transpose in two
// 64-col passes through a wave-private 16x68 LDS slice -> LDS 52.2KB total
// -> 3 blocks/CU (was 2) for +50% NT store queue depth.
#define RT_PER_BLK 4
#define GRID_OUT 6256          // 391 rtg * 16 colg, divisible by 8
#define OBS2 68                // f32 stride (16B-aligned, same bank spread as 132)
__global__ __launch_bounds__(256) void k_gemm_out(const unsigned short* __restrict__ X,
                                                  const unsigned short* __restrict__ Wt,
                                                  const float* __restrict__ bout,
                                                  float* __restrict__ out){
    __shared__ unsigned short Wl[128*136];      // [col][k], 34816 B
    __shared__ float Ob[4*16*OBS2];             // 4 wave-private 16x68 slices, 17408 B
    int obid = (blockIdx.x & 7)*(GRID_OUT/8) + (blockIdx.x >> 3);
    int colg = obid & 15;                       // 16 col groups of 128
    int rtg  = obid >> 4;                       // row-tile group
    int colbase = colg * 128;
    int tid = threadIdx.x;

    #pragma unroll
    for(int i=0; i<8; ++i){
        int chunk = i*256 + tid;                // 0..2047, 8 us each
        int r = chunk >> 4, seg = chunk & 15;
        bf16x8 v = *reinterpret_cast<const bf16x8*>(Wt + (long)(colbase + r)*DIM + seg*8);
        *reinterpret_cast<bf16x8*>(&Wl[r*136 + seg*8]) = v;
    }
    __syncthreads();

    int lane = tid & 63, w = tid >> 6;
    int r16 = lane & 15, ksel = lane >> 4;
    float* ob = Ob + w*16*OBS2;

    bf16x8 bcur[4], bnext[4];
    {
        int row0 = (rtg*RT_PER_BLK + 0)*64 + w*16 + r16;
        int arow = row0 < NN ? row0 : NN-1;
        const unsigned short* xr = X + (long)arow*DIM + ksel*8;
        #pragma unroll
        for(int ks=0; ks<4; ++ks) bcur[ks] = *reinterpret_cast<const bf16x8*>(xr + ks*32);
    }

    #pragma unroll 1
    for(int it=0; it<RT_PER_BLK; ++it){
        int tilebase = (rtg*RT_PER_BLK + it)*64;
        int row = tilebase + w*16 + r16;
        // prefetch next row-tile's X fragments
        if(it+1 < RT_PER_BLK){
            int rown = row + 64;
            int arow = rown < NN ? rown : NN-1;
            const unsigned short* xr = X + (long)arow*DIM + ksel*8;
            #pragma unroll
            for(int ks=0; ks<4; ++ks) bnext[ks] = *reinterpret_cast<const bf16x8*>(xr + ks*32);
        }

        f32x4 acc[8] = {};
        #pragma unroll
        for(int nt=0; nt<8; ++nt){
            const unsigned short* wl = &Wl[(nt*16 + r16)*136 + ksel*8];
            #pragma unroll
            for(int ks=0; ks<4; ++ks){
                bf16x8 a = *reinterpret_cast<const bf16x8*>(wl + ks*32);
                acc[nt] = __builtin_amdgcn_mfma_f32_16x16x32_bf16(a, bcur[ks], acc[nt], 0, 0, 0);
            }
        }

        // epilogue: two 64-col passes through wave-private LDS, NT stores
        {
            const float* br = bout + colbase + ksel*4;
            #pragma unroll
            for(int half=0; half<2; ++half){
                #pragma unroll
                for(int ntl=0; ntl<4; ++ntl){
                    int nt = half*4 + ntl;
                    f32x4 bv = *reinterpret_cast<const f32x4*>(br + nt*16);
                    f32x4 v = acc[nt] + bv;
                    *reinterpret_cast<f32x4*>(&ob[r16*OBS2 + ntl*16 + ksel*4]) = v;
                }
                // same wave reads its own slice: in-order per wave, no barrier
                #pragma unroll
                for(int i=0; i<4; ++i){
                    int lr = i*4 + ksel;
                    int grow = tilebase + w*16 + lr;
                    f32x4 v = *reinterpret_cast<const f32x4*>(&ob[lr*OBS2 + r16*4]);
                    if(grow < NN)
                        __builtin_nontemporal_store(v,
                            reinterpret_cast<f32x4*>(out + (long)grow*NLAB + colbase + half*64 + r16*4));
                }
            }
        }
        #pragma unroll
        for(int ks=0; ks<4; ++ks) bcur[ks] = bnext[ks];
    }
}

extern "C" void kernel_launch(void* const* d_in, const int* in_sizes, int n_in,
                              void* d_out, int out_size, void* d_ws, size_t ws_size,
                              hipStream_t stream){
    const int*   ni  = (const int*)  d_in[0];
    const int*   ei  = (const int*)  d_in[1];
    const float* ew  = (const float*)d_in[2];
    const float* emb = (const float*)d_in[3];
    const float* W1  = (const float*)d_in[4];
    const float* b1  = (const float*)d_in[5];
    const float* W2  = (const float*)d_in[6];
    const float* b2  = (const float*)d_in[7];
    const float* Wo  = (const float*)d_in[8];
    const float* bo  = (const float*)d_in[9];
    float* out = (float*)d_out;
    const int* row = ei;
    const int* col = ei + NE;

    char* ws = (char*)d_ws;
    size_t off = 0;
    auto alloc = [&](size_t bytes){ void* p = ws + off; off += (bytes + 255) & ~size_t(255); return p; };
    int*   cnt    = (int*)  alloc((size_t)NN*8);     // cnt[NN] + deg[NN] contiguous (one memset)
    float* deg    = (float*)(cnt + NN);
    int*   excl   = (int*)  alloc((size_t)NN*4);
    int*   bsum   = (int*)  alloc(512*4);
    int*   start  = (int*)  alloc((size_t)(NN+1)*4);
    int*   cursor = (int*)  alloc((size_t)NN*4);
    float* dinv   = (float*)alloc((size_t)NN*4);
    int2*  epack  = (int2*) alloc((size_t)NE*8);
    unsigned short* Xbf = (unsigned short*)alloc((size_t)NN*DIM*2);
    unsigned short* Hbf = (unsigned short*)alloc((size_t)NN*DIM*2);
    unsigned short* Wot = (unsigned short*)alloc((size_t)NLAB*DIM*2);

    const int nbN = (NN + 255)/256;             // 391

    hipMemsetAsync(cnt, 0, (size_t)NN*8, stream);
    k_setup <<<NB_GATHER + NB_WT + NB_COUNT, 256, 0, stream>>>(ni, emb, Xbf, Wo, Wot, col, ew, cnt, deg);
    k_scan1 <<<nbN, 256, 0, stream>>>(cnt, excl, bsum);
    k_scan23<<<(NN + 511)/512, 512, 0, stream>>>(excl, bsum, start, cursor, deg, dinv);

    // layer 1 GEMM fused with CSR fill (independent after scan23)
    k_l1    <<<NB_G128 + NB_COUNT, 256, 0, stream>>>(Xbf, W1, Hbf, row, col, ew, dinv, cursor, epack);
    k_agg   <<<(NN*64+255)/256, 256, 0, stream>>>(Hbf, start, epack, dinv, b1, Xbf);
    // layer 2
    k_gemm128<<<NB_G128, 256, 0, stream>>>(Xbf, W2, Hbf);
    k_agg    <<<(NN*64+255)/256, 256, 0, stream>>>(Hbf, start, epack, dinv, b2, Xbf);
    // output projection
    k_gemm_out<<<GRID_OUT, 256, 0, stream>>>(Xbf, Wot, bo, out);
}

// Round 15
// 439.830 us; speedup vs baseline: 1.1272x; 1.0241x over previous
//
#include <hip/hip_runtime.h>
#include <hip/hip_bf16.h>
#include <stdint.h>

#define NN 100000
#define NE 1000000
#define DIM 128
#define NLAB 2048

typedef __attribute__((ext_vector_type(8))) short bf16x8;
typedef __attribute__((ext_vector_type(4))) float f32x4;
typedef __attribute__((ext_vector_type(2))) unsigned short us2;
typedef __attribute__((ext_vector_type(4))) unsigned short us4;
typedef __attribute__((ext_vector_type(8))) unsigned short us8;

__device__ __forceinline__ unsigned short f2bf(float f){
    union { float f; unsigned int u; } v; v.f = f;
    unsigned int r = v.u + 0x7FFFu + ((v.u >> 16) & 1u);   // round-to-nearest-even
    return (unsigned short)(r >> 16);
}
__device__ __forceinline__ float bf2f(unsigned short b){
    union { unsigned int u; float f; } v; v.u = ((unsigned int)b) << 16;
    return v.f;
}

// ---------- fused setup: gather+convert | Wout transpose | edge count/deg ----------
#define NB_GATHER 12500   // NN*32/256
#define NB_WT 256
#define NB_COUNT 3907     // ceil(NE/256)
__global__ __launch_bounds__(256) void k_setup(const int* __restrict__ ni,
                                               const float* __restrict__ emb,
                                               unsigned short* __restrict__ xbf,
                                               const float* __restrict__ W,
                                               unsigned short* __restrict__ Wt,
                                               const int* __restrict__ col,
                                               const float* __restrict__ ew,
                                               int* __restrict__ cnt,
                                               float* __restrict__ deg){
    __shared__ float t[32][33];
    int b = blockIdx.x;
    if(b < NB_GATHER){
        int id = b*256 + threadIdx.x;           // NN*32 threads, 4 elems each
        int i = id >> 5, q = (id & 31) << 2;
        float4 v = *reinterpret_cast<const float4*>(&emb[(long)ni[i]*DIM + q]);
        us4 o; o.x = f2bf(v.x); o.y = f2bf(v.y); o.z = f2bf(v.z); o.w = f2bf(v.w);
        *reinterpret_cast<us4*>(&xbf[(long)i*DIM + q]) = o;
    } else if(b < NB_GATHER + NB_WT){
        int bb = b - NB_GATHER;
        int kb = bb & 3;      // 128/32
        int cb = bb >> 2;     // 2048/32
        int ci = threadIdx.x & 31;
        int k0 = threadIdx.x >> 5;
        #pragma unroll
        for(int p=0; p<4; ++p){
            int ki = k0 + p*8;
            t[ki][ci] = W[(long)(kb*32+ki)*NLAB + cb*32 + ci];
        }
        __syncthreads();
        int kk = threadIdx.x & 31;
        int c0 = threadIdx.x >> 5;
        #pragma unroll
        for(int p=0; p<4; ++p){
            int cc = c0 + p*8;
            Wt[(long)(cb*32+cc)*DIM + kb*32 + kk] = f2bf(t[kk][cc]);
        }
    } else {
        int e = (b - NB_GATHER - NB_WT)*256 + threadIdx.x;
        if(e < NE){
            int c = col[e];
            atomicAdd(&cnt[c], 1);
            atomicAdd(&deg[c], ew[e]);
        }
    }
}

// ---------- CSR scans ----------
__global__ void k_scan1(const int* __restrict__ cnt, int* __restrict__ excl,
                        int* __restrict__ bsum){
    __shared__ int s[256];
    int tid = threadIdx.x;
    int i = blockIdx.x*256 + tid;
    int v = (i < NN) ? cnt[i] : 0;
    int x = v;
    s[tid] = x; __syncthreads();
    for(int off=1; off<256; off<<=1){
        int t = (tid >= off) ? s[tid-off] : 0;
        __syncthreads();
        x += t; s[tid] = x;
        __syncthreads();
    }
    if(i < NN) excl[i] = x - v;
    if(tid == 255) bsum[blockIdx.x] = x;
}

#define NB_SCAN1 391
__global__ __launch_bounds__(512) void k_scan23(const int* __restrict__ excl,
                                                const int* __restrict__ bsum,
                                                int* __restrict__ start,
                                                int* __restrict__ cursor,
                                                const float* __restrict__ deg,
                                                float* __restrict__ dinv){
    __shared__ int s[512];
    int tid = threadIdx.x;
    int v = (tid < NB_SCAN1) ? bsum[tid] : 0;
    int x = v;
    s[tid] = x; __syncthreads();
    for(int off=1; off<512; off<<=1){
        int t = (tid >= off) ? s[tid-off] : 0;
        __syncthreads();
        x += t; s[tid] = x;
        __syncthreads();
    }
    int i = blockIdx.x*512 + tid;
    if(i < NN){
        int pb = i >> 8;
        int bpre = pb ? s[pb-1] : 0;
        int st = excl[i] + bpre;
        start[i] = st; cursor[i] = st;
        float d = deg[i] + 1.0f;                // self-loop weight 1
        dinv[i] = rsqrtf(d);
    }
    if(i == 0) start[NN] = NE;
}

// ---------- fused layer-1 GEMM + CSR fill ----------
#define NB_G128 1563      // ceil(NN/64)
__global__ __launch_bounds__(256) void k_l1(const unsigned short* __restrict__ X,
                                            const float* __restrict__ W,
                                            unsigned short* __restrict__ H,
                                            const int* __restrict__ row,
                                            const int* __restrict__ col,
                                            const float* __restrict__ ew,
                                            const float* __restrict__ dinv,
                                            int* __restrict__ cursor,
                                            int2* __restrict__ epack){
    __shared__ unsigned short Wt[DIM][DIM+8];   // [col][k], padded
    int tid = threadIdx.x;
    if(blockIdx.x >= NB_G128){
        int e = (blockIdx.x - NB_G128)*256 + tid;
        if(e < NE){
            int c = col[e];
            int r = row[e];
            float wn = ew[e] * dinv[r];
            int p = atomicAdd(&cursor[c], 1);
            epack[p] = make_int2(r, __float_as_int(wn));
        }
        return;
    }
    #pragma unroll
    for(int t=0; t<64; ++t){
        int idx = tid + t*256;                  // 16384 elems
        int k = idx >> 7, j = idx & 127;
        Wt[j][k] = f2bf(W[k*DIM + j]);
    }
    __syncthreads();

    int lane = tid & 63, w = tid >> 6;
    int rowbase = blockIdx.x*64 + w*16;
    int r16 = lane & 15, ksel = lane >> 4;
    int arow = rowbase + r16; if(arow > NN-1) arow = NN-1;
    const unsigned short* xr = X + (long)arow*DIM;
    bf16x8 a[4];
    #pragma unroll
    for(int ks=0; ks<4; ++ks)
        a[ks] = *reinterpret_cast<const bf16x8*>(&xr[ks*32 + ksel*8]);

    f32x4 acc[8] = {};
    #pragma unroll
    for(int ks=0; ks<4; ++ks){
        #pragma unroll
        for(int nt=0; nt<8; ++nt){
            bf16x8 b = *reinterpret_cast<const bf16x8*>(&Wt[nt*16 + r16][ks*32 + ksel*8]);
            acc[nt] = __builtin_amdgcn_mfma_f32_16x16x32_bf16(a[ks], b, acc[nt], 0, 0, 0);
        }
    }

    int orow0 = rowbase + ksel*4;
    #pragma unroll
    for(int nt=0; nt<8; ++nt){
        int oc = nt*16 + r16;
        #pragma unroll
        for(int r=0; r<4; ++r){
            int orow = orow0 + r;
            if(orow < NN) H[(long)orow*DIM + oc] = f2bf(acc[nt][r]);
        }
    }
}

// ---------- H = X @ W  (NNx128 @ 128x128, bf16 in, bf16 out) ----------
__global__ __launch_bounds__(256) void k_gemm128(const unsigned short* __restrict__ X,
                                                 const float* __restrict__ W,
                                                 unsigned short* __restrict__ H){
    __shared__ unsigned short Wt[DIM][DIM+8];   // [col][k], padded
    int tid = threadIdx.x;
    #pragma unroll
    for(int t=0; t<64; ++t){
        int idx = tid + t*256;                  // 16384 elems
        int k = idx >> 7, j = idx & 127;
        Wt[j][k] = f2bf(W[k*DIM + j]);
    }
    __syncthreads();

    int lane = tid & 63, w = tid >> 6;
    int rowbase = blockIdx.x*64 + w*16;
    int r16 = lane & 15, ksel = lane >> 4;
    int arow = rowbase + r16; if(arow > NN-1) arow = NN-1;
    const unsigned short* xr = X + (long)arow*DIM;
    bf16x8 a[4];
    #pragma unroll
    for(int ks=0; ks<4; ++ks)
        a[ks] = *reinterpret_cast<const bf16x8*>(&xr[ks*32 + ksel*8]);

    f32x4 acc[8] = {};
    #pragma unroll
    for(int ks=0; ks<4; ++ks){
        #pragma unroll
        for(int nt=0; nt<8; ++nt){
            bf16x8 b = *reinterpret_cast<const bf16x8*>(&Wt[nt*16 + r16][ks*32 + ksel*8]);
            acc[nt] = __builtin_amdgcn_mfma_f32_16x16x32_bf16(a[ks], b, acc[nt], 0, 0, 0);
        }
    }

    int orow0 = rowbase + ksel*4;
    #pragma unroll
    for(int nt=0; nt<8; ++nt){
        int oc = nt*16 + r16;
        #pragma unroll
        for(int r=0; r<4; ++r){
            int orow = orow0 + r;
            if(orow < NN) H[(long)orow*DIM + oc] = f2bf(acc[nt][r]);
        }
    }
}

// ---------- fused aggregation: 16 edges in flight per wave ----------
__global__ void k_agg(const unsigned short* __restrict__ H, const int* __restrict__ start,
                      const int2* __restrict__ epack,
                      const float* __restrict__ dinv, const float* __restrict__ bias,
                      unsigned short* __restrict__ Xo){
    int wid  = (blockIdx.x*256 + threadIdx.x) >> 6;   // one wave per node
    int lane = threadIdx.x & 63;
    if(wid >= NN) return;
    int c = wid;
    int q = lane >> 4;
    int f = lane & 15;
    int s = start[c], e = start[c+1];
    float acc[8] = {0.f,0.f,0.f,0.f,0.f,0.f,0.f,0.f};
    for(int p=s; p<e; p+=16){
        int pe0 = p + q, pe1 = p + q + 4, pe2 = p + q + 8, pe3 = p + q + 12;
        int pc0 = pe0 < e ? pe0 : e-1;
        int pc1 = pe1 < e ? pe1 : e-1;
        int pc2 = pe2 < e ? pe2 : e-1;
        int pc3 = pe3 < e ? pe3 : e-1;
        int2 k0 = epack[pc0];
        int2 k1 = epack[pc1];
        int2 k2 = epack[pc2];
        int2 k3 = epack[pc3];
        float sc0 = pe0 < e ? __int_as_float(k0.y) : 0.f;
        float sc1 = pe1 < e ? __int_as_float(k1.y) : 0.f;
        float sc2 = pe2 < e ? __int_as_float(k2.y) : 0.f;
        float sc3 = pe3 < e ? __int_as_float(k3.y) : 0.f;
        us8 h0 = *reinterpret_cast<const us8*>(&H[(long)k0.x*DIM + f*8]);
        us8 h1 = *reinterpret_cast<const us8*>(&H[(long)k1.x*DIM + f*8]);
        us8 h2 = *reinterpret_cast<const us8*>(&H[(long)k2.x*DIM + f*8]);
        us8 h3 = *reinterpret_cast<const us8*>(&H[(long)k3.x*DIM + f*8]);
        #pragma unroll
        for(int j=0;j<8;++j)
            acc[j] += (sc0 * bf2f(h0[j]) + sc1 * bf2f(h1[j]))
                    + (sc2 * bf2f(h2[j]) + sc3 * bf2f(h3[j]));
    }
    #pragma unroll
    for(int j=0;j<8;++j){
        acc[j] += __shfl_xor(acc[j], 16);
        acc[j] += __shfl_xor(acc[j], 32);
    }
    if(q == 0){
        float dc = dinv[c];
        us8 hc = *reinterpret_cast<const us8*>(&H[(long)c*DIM + f*8]);
        us8 o;
        #pragma unroll
        for(int j=0;j<8;++j){
            float v = dc*(acc[j] + dc*bf2f(hc[j])) + bias[f*8+j];
            v = v > 0.f ? v : 0.f;
            o[j] = f2bf(v);
        }
        *reinterpret_cast<us8*>(&Xo[(long)c*DIM + f*8]) = o;
    }
}

// ---------- out = X @ Wout + bout ----------
// Validated best epilogue (R12): wave-private LDS transpose (no barrier) ->
// 1KB-contiguous NT stores. NT beats plain (+56us: bypasses L2, preserves
// operand working set); contiguity beats scattered 64B segments (+40us).
#define RT_PER_BLK 4
#define GRID_OUT 6256          // 391 rtg * 16 colg, divisible by 8
#define OBS 132                // f32 stride of Ob row (16B-aligned, bank-uniform)
__global__ __launch_bounds__(256) void k_gemm_out(const unsigned short* __restrict__ X,
                                                  const unsigned short* __restrict__ Wt,
                                                  const float* __restrict__ bout,
                                                  float* __restrict__ out){
    __shared__ unsigned short Wl[128*136];      // [col][k], 34816 B
    __shared__ float Ob[4*16*OBS];              // 4 wave-private 16x132 slices, 33792 B
    int obid = (blockIdx.x & 7)*(GRID_OUT/8) + (blockIdx.x >> 3);
    int colg = obid & 15;                       // 16 col groups of 128
    int rtg  = obid >> 4;                       // row-tile group
    int colbase = colg * 128;
    int tid = threadIdx.x;

    #pragma unroll
    for(int i=0; i<8; ++i){
        int chunk = i*256 + tid;                // 0..2047, 8 us each
        int r = chunk >> 4, seg = chunk & 15;
        bf16x8 v = *reinterpret_cast<const bf16x8*>(Wt + (long)(colbase + r)*DIM + seg*8);
        *reinterpret_cast<bf16x8*>(&Wl[r*136 + seg*8]) = v;
    }
    __syncthreads();

    int lane = tid & 63, w = tid >> 6;
    int r16 = lane & 15, ksel = lane >> 4;
    float* ob = Ob + w*16*OBS;
    int l32 = lane & 31, lh = lane >> 5;

    bf16x8 bcur[4], bnext[4];
    {
        int row0 = (rtg*RT_PER_BLK + 0)*64 + w*16 + r16;
        int arow = row0 < NN ? row0 : NN-1;
        const unsigned short* xr = X + (long)arow*DIM + ksel*8;
        #pragma unroll
        for(int ks=0; ks<4; ++ks) bcur[ks] = *reinterpret_cast<const bf16x8*>(xr + ks*32);
    }

    #pragma unroll 1
    for(int it=0; it<RT_PER_BLK; ++it){
        int tilebase = (rtg*RT_PER_BLK + it)*64;
        int row = tilebase + w*16 + r16;
        // prefetch next row-tile's X fragments
        if(it+1 < RT_PER_BLK){
            int rown = row + 64;
            int arow = rown < NN ? rown : NN-1;
            const unsigned short* xr = X + (long)arow*DIM + ksel*8;
            #pragma unroll
            for(int ks=0; ks<4; ++ks) bnext[ks] = *reinterpret_cast<const bf16x8*>(xr + ks*32);
        }

        f32x4 acc[8] = {};
        #pragma unroll
        for(int nt=0; nt<8; ++nt){
            const unsigned short* wl = &Wl[(nt*16 + r16)*136 + ksel*8];
            #pragma unroll
            for(int ks=0; ks<4; ++ks){
                bf16x8 a = *reinterpret_cast<const bf16x8*>(wl + ks*32);
                acc[nt] = __builtin_amdgcn_mfma_f32_16x16x32_bf16(a, bcur[ks], acc[nt], 0, 0, 0);
            }
        }

        // epilogue: bias -> wave-private LDS (row r16) -> contiguous NT stores
        {
            const float* br = bout + colbase + ksel*4;
            #pragma unroll
            for(int nt=0; nt<8; ++nt){
                f32x4 bv = *reinterpret_cast<const f32x4*>(br + nt*16);
                f32x4 v = acc[nt] + bv;
                *reinterpret_cast<f32x4*>(&ob[r16*OBS + nt*16 + ksel*4]) = v;
            }
            // same wave reads its own slice: in-order LDS per wave, no barrier
            #pragma unroll
            for(int i=0; i<8; ++i){
                int lr = i*2 + lh;
                int grow = tilebase + w*16 + lr;
                f32x4 v = *reinterpret_cast<const f32x4*>(&ob[lr*OBS + l32*4]);
                if(grow < NN)
                    __builtin_nontemporal_store(v,
                        reinterpret_cast<f32x4*>(out + (long)grow*NLAB + colbase + l32*4));
            }
        }
        #pragma unroll
        for(int ks=0; ks<4; ++ks) bcur[ks] = bnext[ks];
    }
}

extern "C" void kernel_launch(void* const* d_in, const int* in_sizes, int n_in,
                              void* d_out, int out_size, void* d_ws, size_t ws_size,
                              hipStream_t stream){
    const int*   ni  = (const int*)  d_in[0];
    const int*   ei  = (const int*)  d_in[1];
    const float* ew  = (const float*)d_in[2];
    const float* emb = (const float*)d_in[3];
    const float* W1  = (const float*)d_in[4];
    const float* b1  = (const float*)d_in[5];
    const float* W2  = (const float*)d_in[6];
    const float* b2  = (const float*)d_in[7];
    const float* Wo  = (const float*)d_in[8];
    const float* bo  = (const float*)d_in[9];
    float* out = (float*)d_out;
    const int* row = ei;
    const int* col = ei + NE;

    char* ws = (char*)d_ws;
    size_t off = 0;
    auto alloc = [&](size_t bytes){ void* p = ws + off; off += (bytes + 255) & ~size_t(255); return p; };
    int*   cnt    = (int*)  alloc((size_t)NN*8);     // cnt[NN] + deg[NN] contiguous (one memset)
    float* deg    = (float*)(cnt + NN);
    int*   excl   = (int*)  alloc((size_t)NN*4);
    int*   bsum   = (int*)  alloc(512*4);
    int*   start  = (int*)  alloc((size_t)(NN+1)*4);
    int*   cursor = (int*)  alloc((size_t)NN*4);
    float* dinv   = (float*)alloc((size_t)NN*4);
    int2*  epack  = (int2*) alloc((size_t)NE*8);
    unsigned short* Xbf = (unsigned short*)alloc((size_t)NN*DIM*2);
    unsigned short* Hbf = (unsigned short*)alloc((size_t)NN*DIM*2);
    unsigned short* Wot = (unsigned short*)alloc((size_t)NLAB*DIM*2);

    const int nbN = (NN + 255)/256;             // 391

    hipMemsetAsync(cnt, 0, (size_t)NN*8, stream);
    k_setup <<<NB_GATHER + NB_WT + NB_COUNT, 256, 0, stream>>>(ni, emb, Xbf, Wo, Wot, col, ew, cnt, deg);
    k_scan1 <<<nbN, 256, 0, stream>>>(cnt, excl, bsum);
    k_scan23<<<(NN + 511)/512, 512, 0, stream>>>(excl, bsum, start, cursor, deg, dinv);

    // layer 1 GEMM fused with CSR fill (independent after scan23)
    k_l1    <<<NB_G128 + NB_COUNT, 256, 0, stream>>>(Xbf, W1, Hbf, row, col, ew, dinv, cursor, epack);
    k_agg   <<<(NN*64+255)/256, 256, 0, stream>>>(Hbf, start, epack, dinv, b1, Xbf);
    // layer 2
    k_gemm128<<<NB_G128, 256, 0, stream>>>(Xbf, W2, Hbf);
    k_agg    <<<(NN*64+255)/256, 256, 0, stream>>>(Hbf, start, epack, dinv, b2, Xbf);
    // output projection
    k_gemm_out<<<GRID_OUT, 256, 0, stream>>>(Xbf, Wot, bo, out);
}